// Round 1
// 1200.519 us; speedup vs baseline: 1.0114x; 1.0114x over previous
//
#include <hip/hip_runtime.h>
#include <stdint.h>

#define MAX_DEG   10
#define DEG_COUNT 30000
#define N_ATOMS   330000      // 11 * 30000
#define NF        128
#define BATCH     128

typedef __attribute__((ext_vector_type(8))) short bf16x8;   // 8 bf16 (4 VGPRs)
typedef __attribute__((ext_vector_type(4))) float f32x4;

__device__ __forceinline__ float bf2f(unsigned short h) {
  union { unsigned u; float f; } v; v.u = ((unsigned)h) << 16; return v.f;
}
__device__ __forceinline__ unsigned short f2bf(float f) {
  union { float f; unsigned u; } v; v.f = f;
  unsigned u = v.u;
  unsigned r = (u + 0x7fffu + ((u >> 16) & 1u)) >> 16;   // RNE
  return (unsigned short)r;
}

struct AdjPtrs { const int* p[10]; };

#define NEG_INF_BITS 0xFF800000

// ---------------------------------------------------------------------------
// K_init: zero gsum, -inf gmax (ws is re-poisoned before every launch).
// ---------------------------------------------------------------------------
__global__ __launch_bounds__(256) void k_init(float* __restrict__ gsum,
                                              int* __restrict__ gmax) {
  int i = blockIdx.x * 256 + threadIdx.x;
  if (i < BATCH * 128) { gsum[i] = 0.f; gmax[i] = (int)NEG_INF_BITS; }
}

// ---------------------------------------------------------------------------
// K0: cast fp32 atoms -> bf16 copy (GEMM A-source + gather source, L3-resident)
// ---------------------------------------------------------------------------
__global__ __launch_bounds__(256) void k_cast(const float4* __restrict__ src,
                                              ushort4* __restrict__ dst) {
  size_t i = (size_t)blockIdx.x * 256 + threadIdx.x;   // one float4 -> ushort4
  float4 v = src[i];
  ushort4 o;
  o.x = f2bf(v.x); o.y = f2bf(v.y); o.z = f2bf(v.z); o.w = f2bf(v.w);
  dst[i] = o;
}

// ---------------------------------------------------------------------------
// K1a: build BcatT[d][n][k] (bf16), n,k in [0,256), from fp32 W.
// Virtual B[d][k][n]: k<128 -> neigh (Wrel | 0), k>=128 -> self (Wself | Wg)
// ---------------------------------------------------------------------------
__global__ __launch_bounds__(256) void k_build_b(const float* __restrict__ W,
                                                 unsigned short* __restrict__ BcatT) {
  int idx = blockIdx.x * 256 + threadIdx.x;
  if (idx >= 11 * 256 * 256) return;
  int d = idx >> 16;
  int rem = idx & 65535;
  int n = rem >> 8;
  int k = rem & 255;
  float v = 0.f;
  if (k < 128) {
    if (n < 128 && d >= 1) v = W[(2 * (d - 1)) * 16384 + k * 128 + n];
  } else {
    int ks = k - 128;
    if (n < 128) { int wi = (d >= 1) ? (2 * d - 1) : 20; v = W[wi * 16384 + ks * 128 + n]; }
    else         { int wi = (d >= 1) ? (20 + d)   : 31; v = W[wi * 16384 + ks * 128 + (n - 128)]; }
  }
  BcatT[idx] = f2bf(v);   // idx == d*65536 + n*256 + k
}

// K1b: biascat[d][n] f32: n<128 -> b_rel + b_self (activated), n>=128 -> b_gather
__global__ __launch_bounds__(256) void k_build_bias(const float* __restrict__ b,
                                                    float* __restrict__ biascat) {
  int idx = blockIdx.x * 256 + threadIdx.x;
  if (idx >= 11 * 256) return;
  int d = idx >> 8, n = idx & 255;
  float f;
  if (n < 128) {
    if (d >= 1) f = b[(2 * (d - 1)) * 128 + n] + b[(2 * d - 1) * 128 + n];
    else        f = b[20 * 128 + n];
  } else {
    int j = n - 128;
    f = (d >= 1) ? b[(20 + d) * 128 + j] : b[31 * 128 + j];
  }
  biascat[idx] = f;
}

// ---------------------------------------------------------------------------
// K2: neighbor sums from bf16 atom copy. One wave per atom row; lane = 2 cols.
// deg-0 rows written as zeros (B zero-block makes them inert).
// ---------------------------------------------------------------------------
__global__ __launch_bounds__(256) void k_nsum(const unsigned* __restrict__ atomsU,
                                              AdjPtrs adj,
                                              unsigned* __restrict__ nsumU) {
  int wave = threadIdx.x >> 6;
  int lane = threadIdx.x & 63;
  int row = blockIdx.x * 4 + wave;
  if (row >= N_ATOMS) return;
  int d = row / DEG_COUNT;
  if (d == 0) { nsumU[row * 64 + lane] = 0u; return; }
  int r = row - d * DEG_COUNT;
  const int* a = adj.p[d - 1];
  float s0 = 0.f, s1 = 0.f;
  for (int j = 0; j < d; ++j) {
    int nbr = a[r * d + j];
    unsigned x = atomsU[nbr * 64 + lane];
    s0 += bf2f((unsigned short)(x & 0xffff));
    s1 += bf2f((unsigned short)(x >> 16));
  }
  nsumU[row * 64 + lane] = (unsigned)f2bf(s0) | ((unsigned)f2bf(s1) << 16);
}

// ---------------------------------------------------------------------------
// K3: fused tiled MFMA GEMM. One block = 128 rows x 256 outputs (128 activated
// + 128 gathered), K=256, 512 threads (8 waves, 2 row x 4 col). A is fetched
// ONCE per block (was 2x via grid.z). Epilogue stages results through LDS:
//  - activated: fp32 staged, per-row LayerNorm (shfl reduce), final xn written
//    with fully coalesced 512B/wave-row stores (no separate norm pass).
//  - gathered: bf16 staged, 256B/wave-row coalesced stores.
// Next-k0 register prefetch overlaps HBM latency with MFMA.
// ---------------------------------------------------------------------------
__global__ __launch_bounds__(512) void k_gemm(
    const unsigned short* __restrict__ atomsBf,
    const unsigned short* __restrict__ nsum,
    const unsigned short* __restrict__ BcatT,    // [11][256][256] n-major
    const float* __restrict__ biascat,           // [11][256]
    const float* __restrict__ gamma,
    const float* __restrict__ beta,
    float* __restrict__ out0,                    // xn FINAL (fp32)
    unsigned short* __restrict__ gath)           // gathered ws (bf16)
{
  const int d = blockIdx.y;
  const int rowTile = blockIdx.x;
  const int tid = threadIdx.x;
  const int lane = tid & 63;
  const int wave = tid >> 6;          // 0..7
  const int waveRow = wave & 1;       // 2 row-halves of 64
  const int waveCol = wave >> 1;      // 4 col-quarters of 64 (256 cols)

  // 55296 B raw LDS, multi-purpose:
  //  GEMM:    As[128][72] shorts (18432B) + Bs[256][72] shorts (36864B)
  //  Epilog:  SA[64][132] fp32 (33792B) + SG[64][136] shorts (17408B)
  __shared__ uint4 ldsRaw[55296 / 16];
  unsigned short* As = (unsigned short*)ldsRaw;
  unsigned short* Bs = As + 128 * 72;
  float* SA = (float*)ldsRaw;
  unsigned short* SG = (unsigned short*)((char*)ldsRaw + 64 * 132 * 4);

  f32x4 acc[4][4];
#pragma unroll
  for (int i = 0; i < 4; i++)
#pragma unroll
    for (int j = 0; j < 4; j++) acc[i][j] = (f32x4){0.f, 0.f, 0.f, 0.f};

  const unsigned short* Bd = BcatT + d * 65536;

  auto loadK = [&](int k0, uint4* aReg, uint4* bReg) {
#pragma unroll
    for (int c = 0; c < 2; ++c) {
      int flat = c * 512 + tid;           // 0..1023 : A tile 128x64 bf16
      int rl = flat >> 3;
      int col8 = (flat & 7) << 3;
      int rb = rowTile * 128 + rl; if (rb > DEG_COUNT - 1) rb = DEG_COUNT - 1;
      size_t grow = (size_t)(d * DEG_COUNT + rb);
      const unsigned short* srcA = (k0 < 2)
          ? (nsum    + grow * 128 + k0 * 64 + col8)
          : (atomsBf + grow * 128 + (k0 - 2) * 64 + col8);
      aReg[c] = *(const uint4*)srcA;
    }
#pragma unroll
    for (int c = 0; c < 4; ++c) {
      int flat = c * 512 + tid;           // 0..2047 : B tile 256x64 bf16
      int rl = flat >> 3;
      int col8 = (flat & 7) << 3;
      bReg[c] = *(const uint4*)(Bd + rl * 256 + k0 * 64 + col8);
    }
  };
  auto storeK = [&](const uint4* aReg, const uint4* bReg) {
#pragma unroll
    for (int c = 0; c < 2; ++c) {
      int flat = c * 512 + tid;
      int rl = flat >> 3;
      int col8 = (flat & 7) << 3;
      *(uint4*)(&As[rl * 72 + col8]) = aReg[c];
    }
#pragma unroll
    for (int c = 0; c < 4; ++c) {
      int flat = c * 512 + tid;
      int rl = flat >> 3;
      int col8 = (flat & 7) << 3;
      *(uint4*)(&Bs[rl * 72 + col8]) = bReg[c];
    }
  };
  auto compute = [&]() {
#pragma unroll
    for (int ks = 0; ks < 2; ++ks) {
      bf16x8 afrag[4], bfrag[4];
      int kofs = ks * 32 + (lane >> 4) * 8;
      int m16 = lane & 15;
#pragma unroll
      for (int rt = 0; rt < 4; ++rt)
        afrag[rt] = *(const bf16x8*)(&As[(waveRow * 64 + rt * 16 + m16) * 72 + kofs]);
#pragma unroll
      for (int ct = 0; ct < 4; ++ct)
        bfrag[ct] = *(const bf16x8*)(&Bs[(waveCol * 64 + ct * 16 + m16) * 72 + kofs]);
#pragma unroll
      for (int rt = 0; rt < 4; ++rt)
#pragma unroll
        for (int ct = 0; ct < 4; ++ct)
          acc[rt][ct] = __builtin_amdgcn_mfma_f32_16x16x32_bf16(afrag[rt], bfrag[ct], acc[rt][ct], 0, 0, 0);
    }
  };

  uint4 aCur[2], bCur[4], aNxt[2], bNxt[4];
  loadK(0, aCur, bCur);
#pragma unroll
  for (int k0 = 0; k0 < 4; ++k0) {
    __syncthreads();
    storeK(aCur, bCur);
    __syncthreads();
    if (k0 < 3) loadK(k0 + 1, aNxt, bNxt);   // prefetch overlaps compute
    compute();
#pragma unroll
    for (int c = 0; c < 2; ++c) aCur[c] = aNxt[c];
#pragma unroll
    for (int c = 0; c < 4; ++c) bCur[c] = bNxt[c];
  }

  // ---- epilogue: bias add -> LDS stage -> LayerNorm + coalesced stores ----
  const int m16 = lane & 15, quad = lane >> 4;
  float g0 = gamma[2 * lane], g1 = gamma[2 * lane + 1];
  float b0 = beta[2 * lane],  b1 = beta[2 * lane + 1];

#pragma unroll
  for (int h = 0; h < 2; ++h) {       // two row-halves of 64
    __syncthreads();                  // LDS safe to overwrite / next pass
    if (waveRow == h) {
#pragma unroll
      for (int ct = 0; ct < 4; ++ct) {
        int col = waveCol * 64 + ct * 16 + m16;       // 0..255
        float bias = biascat[d * 256 + col];
#pragma unroll
        for (int rt = 0; rt < 4; ++rt) {
#pragma unroll
          for (int r = 0; r < 4; ++r) {
            int rowl = rt * 16 + quad * 4 + r;        // 0..63 local
            float v = acc[rt][ct][r] + bias;
            if (col < 128) SA[rowl * 132 + col] = v;
            else           SG[rowl * 136 + (col - 128)] = f2bf(v);
          }
        }
      }
    }
    __syncthreads();
    // all 8 waves: wave handles local rows wave*8 .. wave*8+7
#pragma unroll
    for (int i = 0; i < 8; ++i) {
      int lr = wave * 8 + i;
      int rb = rowTile * 128 + h * 64 + lr;
      if (rb >= DEG_COUNT) continue;                  // wave-uniform
      size_t grow = (size_t)(d * DEG_COUNT + rb);
      float2 x = *(const float2*)(SA + lr * 132 + 2 * lane);
      float s = x.x + x.y, q = x.x * x.x + x.y * x.y;
#pragma unroll
      for (int off = 32; off >= 1; off >>= 1) {
        s += __shfl_xor(s, off, 64);
        q += __shfl_xor(q, off, 64);
      }
      float mean = s * (1.0f / 128.0f);
      float var  = q * (1.0f / 128.0f) - mean * mean;
      float inv  = 1.0f / (sqrtf(var + 1e-5f) + 1e-5f);   // ref: sqrt(var+eps)+eps
      float a0 = g0 * ((x.x - mean) * inv) + b0;
      float a1 = g1 * ((x.y - mean) * inv) + b1;
      *(float2*)(out0 + grow * 128 + 2 * lane) = make_float2(a0, a1);
      *(ushort2*)(gath + grow * 128 + 2 * lane) = *(const ushort2*)(SG + lr * 136 + 2 * lane);
    }
  }
}

// ---------------------------------------------------------------------------
// K4: read-only segment-max of final xn via per-block LDS table + monotonic
// int atomics (LN already applied inside k_gemm).
// ---------------------------------------------------------------------------
__global__ __launch_bounds__(512) void k_max(
    const float2* __restrict__ xnV,
    const int* __restrict__ membership,
    int* __restrict__ gmax)
{
  __shared__ int pmax[BATCH * 128];
  int tid = threadIdx.x;
  for (int i = tid; i < BATCH * 128; i += 512) pmax[i] = (int)NEG_INF_BITS;
  __syncthreads();
  int wave = tid >> 6, lane = tid & 63;
  const int rowsPerBlock = (N_ATOMS + gridDim.x - 1) / gridDim.x;
  int r0 = blockIdx.x * rowsPerBlock;
  int r1 = min(r0 + rowsPerBlock, N_ATOMS);
  for (int r = r0 + wave; r < r1; r += 8) {
    float2 x = xnV[(size_t)r * 64 + lane];
    int m = membership[r];
    int idx = m * 128 + lane * 2;
    if (x.x >= 0.f) atomicMax(&pmax[idx], __float_as_int(x.x));
    else            atomicMin((unsigned*)&pmax[idx], __float_as_uint(x.x));
    if (x.y >= 0.f) atomicMax(&pmax[idx + 1], __float_as_int(x.y));
    else            atomicMin((unsigned*)&pmax[idx + 1], __float_as_uint(x.y));
  }
  __syncthreads();
  for (int i = tid; i < BATCH * 128; i += 512) {
    int v = pmax[i];
    if (v != (int)NEG_INF_BITS) {
      if (v >= 0) atomicMax(&gmax[i], v);
      else        atomicMin((unsigned*)&gmax[i], (unsigned)v);
    }
  }
}

// K5: per-block LDS segment-sum of gathered (bf16 ws), merged via atomicAdd.
__global__ __launch_bounds__(512) void k_segsum(
    const unsigned* __restrict__ gathU,
    const int* __restrict__ membership,
    float* __restrict__ gsum)
{
  __shared__ float psum[BATCH * 128];
  int tid = threadIdx.x;
  for (int i = tid; i < BATCH * 128; i += 512) psum[i] = 0.f;
  __syncthreads();
  int wave = tid >> 6, lane = tid & 63;
  const int rowsPerBlock = (N_ATOMS + gridDim.x - 1) / gridDim.x;
  int r0 = blockIdx.x * rowsPerBlock;
  int r1 = min(r0 + rowsPerBlock, N_ATOMS);
  for (int r = r0 + wave; r < r1; r += 8) {
    unsigned x = gathU[(size_t)r * 64 + lane];
    int m = membership[r];
    atomicAdd(&psum[m * 128 + lane * 2],     bf2f((unsigned short)(x & 0xffff)));
    atomicAdd(&psum[m * 128 + lane * 2 + 1], bf2f((unsigned short)(x >> 16)));
  }
  __syncthreads();
  for (int i = tid; i < BATCH * 128; i += 512) {
    float v = psum[i];
    if (v != 0.f) atomicAdd(&gsum[i], v);
  }
}

// K6: norm gsum -> yn (out1); gmax -> g (out2). fp32.
__global__ __launch_bounds__(128) void k_final(
    const float* __restrict__ gsum,
    const int* __restrict__ gmax,
    const float* __restrict__ gamma,
    const float* __restrict__ beta,
    float* __restrict__ out1,
    float* __restrict__ out2)
{
  int m = blockIdx.x;
  int j = threadIdx.x;
  float s = gsum[m * 128 + j];
  out2[m * 128 + j] = __int_as_float(gmax[m * 128 + j]);

  float ws_ = s, wq = s * s;
#pragma unroll
  for (int off = 32; off >= 1; off >>= 1) {
    ws_ += __shfl_xor(ws_, off, 64);
    wq  += __shfl_xor(wq, off, 64);
  }
  __shared__ float red[4];
  int wave = j >> 6, lane = j & 63;
  if (lane == 0) { red[wave * 2] = ws_; red[wave * 2 + 1] = wq; }
  __syncthreads();
  float S = red[0] + red[2], Q = red[1] + red[3];
  float mean = S * (1.f / 128.f);
  float var = Q * (1.f / 128.f) - mean * mean;
  float inv = 1.f / (sqrtf(var + 1e-5f) + 1e-5f);
  float yn = gamma[j] * ((s - mean) * inv) + beta[j];
  out1[m * 128 + j] = yn;
}

// ---------------------------------------------------------------------------
extern "C" void kernel_launch(void* const* d_in, const int* in_sizes, int n_in,
                              void* d_out, int out_size, void* d_ws, size_t ws_size,
                              hipStream_t stream) {
  const float* atoms = (const float*)d_in[0];
  // d_in[1] = deg_slice (unused; buckets are static)
  const int* membership = (const int*)d_in[2];
  AdjPtrs adj;
  for (int i = 0; i < 10; ++i) adj.p[i] = (const int*)d_in[3 + i];
  const float* W     = (const float*)d_in[13];
  const float* b     = (const float*)d_in[14];
  const float* gamma = (const float*)d_in[15];
  const float* beta  = (const float*)d_in[16];

  char* ws = (char*)d_ws;
  size_t off = 0;
  unsigned short* atomsBf = (unsigned short*)(ws + off); off += (size_t)N_ATOMS * 128 * 2;
  unsigned short* nsum    = (unsigned short*)(ws + off); off += (size_t)N_ATOMS * 128 * 2;
  unsigned short* gath    = (unsigned short*)(ws + off); off += (size_t)N_ATOMS * 128 * 2;
  unsigned short* BcatT   = (unsigned short*)(ws + off); off += (size_t)11 * 256 * 256 * 2;
  float* biascat          = (float*)(ws + off);          off += (size_t)11 * 256 * 4;
  float* gsum             = (float*)(ws + off);          off += (size_t)BATCH * 128 * 4;
  int*   gmax             = (int*)(ws + off);            off += (size_t)BATCH * 128 * 4;

  float* out0 = (float*)d_out;
  float* out1 = out0 + (size_t)N_ATOMS * 128;
  float* out2 = out1 + 16384;

  hipLaunchKernelGGL(k_init, dim3((BATCH * 128 + 255) / 256), dim3(256), 0, stream, gsum, gmax);
  hipLaunchKernelGGL(k_cast, dim3(N_ATOMS * 128 / 4 / 256), dim3(256), 0, stream,
                     (const float4*)atoms, (ushort4*)atomsBf);
  hipLaunchKernelGGL(k_build_b, dim3((11 * 256 * 256 + 255) / 256), dim3(256), 0, stream, W, BcatT);
  hipLaunchKernelGGL(k_build_bias, dim3((11 * 256 + 255) / 256), dim3(256), 0, stream, b, biascat);
  hipLaunchKernelGGL(k_nsum, dim3(N_ATOMS / 4), dim3(256), 0, stream,
                     (const unsigned*)atomsBf, adj, (unsigned*)nsum);
  hipLaunchKernelGGL(k_gemm, dim3(235, 11), dim3(512), 0, stream,
                     atomsBf, nsum, BcatT, biascat, gamma, beta, out0, gath);
  hipLaunchKernelGGL(k_max, dim3(512), dim3(512), 0, stream,
                     (const float2*)out0, membership, gmax);
  hipLaunchKernelGGL(k_segsum, dim3(512), dim3(512), 0, stream,
                     (const unsigned*)gath, membership, gsum);
  hipLaunchKernelGGL(k_final, dim3(128), dim3(128), 0, stream,
                     gsum, gmax, gamma, beta, out1, out2);
}

// Round 2
// 899.068 us; speedup vs baseline: 1.3506x; 1.3353x over previous
//
#include <hip/hip_runtime.h>
#include <stdint.h>

#define MAX_DEG   10
#define DEG_COUNT 30000
#define N_ATOMS   330000      // 11 * 30000
#define NF        128
#define BATCH     128

typedef __attribute__((ext_vector_type(8))) short bf16x8;   // 8 bf16 (4 VGPRs)
typedef __attribute__((ext_vector_type(4))) float f32x4;

__device__ __forceinline__ float bf2f(unsigned short h) {
  union { unsigned u; float f; } v; v.u = ((unsigned)h) << 16; return v.f;
}
__device__ __forceinline__ unsigned short f2bf(float f) {
  union { float f; unsigned u; } v; v.f = f;
  unsigned u = v.u;
  unsigned r = (u + 0x7fffu + ((u >> 16) & 1u)) >> 16;   // RNE
  return (unsigned short)r;
}

struct AdjPtrs { const int* p[10]; };

#define NEG_INF_BITS 0xFF800000

// ---------------------------------------------------------------------------
// K_init: zero gsum, -inf gmax (ws is re-poisoned before every launch).
// ---------------------------------------------------------------------------
__global__ __launch_bounds__(256) void k_init(float* __restrict__ gsum,
                                              int* __restrict__ gmax) {
  int i = blockIdx.x * 256 + threadIdx.x;
  if (i < BATCH * 128) { gsum[i] = 0.f; gmax[i] = (int)NEG_INF_BITS; }
}

// ---------------------------------------------------------------------------
// K0: cast fp32 atoms -> bf16 copy (GEMM A-source + gather source, L3-resident)
// ---------------------------------------------------------------------------
__global__ __launch_bounds__(256) void k_cast(const float4* __restrict__ src,
                                              ushort4* __restrict__ dst) {
  size_t i = (size_t)blockIdx.x * 256 + threadIdx.x;   // one float4 -> ushort4
  float4 v = src[i];
  ushort4 o;
  o.x = f2bf(v.x); o.y = f2bf(v.y); o.z = f2bf(v.z); o.w = f2bf(v.w);
  dst[i] = o;
}

// ---------------------------------------------------------------------------
// K1a: build BcatT[d][n][k] (bf16), n,k in [0,256), from fp32 W.
// Virtual B[d][k][n]: k<128 -> neigh (Wrel | 0), k>=128 -> self (Wself | Wg)
// ---------------------------------------------------------------------------
__global__ __launch_bounds__(256) void k_build_b(const float* __restrict__ W,
                                                 unsigned short* __restrict__ BcatT) {
  int idx = blockIdx.x * 256 + threadIdx.x;
  if (idx >= 11 * 256 * 256) return;
  int d = idx >> 16;
  int rem = idx & 65535;
  int n = rem >> 8;
  int k = rem & 255;
  float v = 0.f;
  if (k < 128) {
    if (n < 128 && d >= 1) v = W[(2 * (d - 1)) * 16384 + k * 128 + n];
  } else {
    int ks = k - 128;
    if (n < 128) { int wi = (d >= 1) ? (2 * d - 1) : 20; v = W[wi * 16384 + ks * 128 + n]; }
    else         { int wi = (d >= 1) ? (20 + d)   : 31; v = W[wi * 16384 + ks * 128 + (n - 128)]; }
  }
  BcatT[idx] = f2bf(v);   // idx == d*65536 + n*256 + k
}

// K1b: biascat[d][n] f32: n<128 -> b_rel + b_self (activated), n>=128 -> b_gather
__global__ __launch_bounds__(256) void k_build_bias(const float* __restrict__ b,
                                                    float* __restrict__ biascat) {
  int idx = blockIdx.x * 256 + threadIdx.x;
  if (idx >= 11 * 256) return;
  int d = idx >> 8, n = idx & 255;
  float f;
  if (n < 128) {
    if (d >= 1) f = b[(2 * (d - 1)) * 128 + n] + b[(2 * d - 1) * 128 + n];
    else        f = b[20 * 128 + n];
  } else {
    int j = n - 128;
    f = (d >= 1) ? b[(20 + d) * 128 + j] : b[31 * 128 + j];
  }
  biascat[idx] = f;
}

// ---------------------------------------------------------------------------
// K2: neighbor sums from bf16 atom copy. One wave per atom row; lane = 2 cols.
// deg-0 rows written as zeros (B zero-block makes them inert).
// ---------------------------------------------------------------------------
__global__ __launch_bounds__(256) void k_nsum(const unsigned* __restrict__ atomsU,
                                              AdjPtrs adj,
                                              unsigned* __restrict__ nsumU) {
  int wave = threadIdx.x >> 6;
  int lane = threadIdx.x & 63;
  int row = blockIdx.x * 4 + wave;
  if (row >= N_ATOMS) return;
  int d = row / DEG_COUNT;
  if (d == 0) { nsumU[row * 64 + lane] = 0u; return; }
  int r = row - d * DEG_COUNT;
  const int* a = adj.p[d - 1];
  float s0 = 0.f, s1 = 0.f;
  for (int j = 0; j < d; ++j) {
    int nbr = a[r * d + j];
    unsigned x = atomsU[nbr * 64 + lane];
    s0 += bf2f((unsigned short)(x & 0xffff));
    s1 += bf2f((unsigned short)(x >> 16));
  }
  nsumU[row * 64 + lane] = (unsigned)f2bf(s0) | ((unsigned)f2bf(s1) << 16);
}

// ---------------------------------------------------------------------------
// K3: barrier-free streaming MFMA GEMM.
//  - B[256][256] bf16 for this degree staged ONCE into 128KB LDS, XOR-swizzled
//    (kbyte ^= (row&7)<<4) so B-frag ds_read_b128 at 512B row stride is 2-way.
//  - ONE __syncthreads() per block (after B stage).
//  - A loaded global->VGPR directly in MFMA fragment layout (no LDS, no sync):
//    lane reads row m16's 16B at k = ks*32 + g*8; wave = 16 rows x 64B coalesced.
//  - Each wave owns 32 rows (2 x 16-row chunks); both chunks' A-frags hoisted
//    before the barrier so global latency hides under barrier + compute.
//  - LN epilogue straight from accumulators: C layout col=lane&15,
//    row=quad*4+reg -> row-sum = 4x shfl_xor over the m16 group. No barriers.
// ---------------------------------------------------------------------------
__global__ __launch_bounds__(512, 2) void k_gemm(
    const unsigned short* __restrict__ atomsBf,
    const unsigned short* __restrict__ nsum,
    const unsigned short* __restrict__ BcatT,    // [11][256][256] n-major
    const float* __restrict__ biascat,           // [11][256]
    const float* __restrict__ gamma,
    const float* __restrict__ beta,
    float* __restrict__ out0,                    // xn FINAL (fp32)
    unsigned short* __restrict__ gath)           // gathered ws (bf16)
{
  const int d = blockIdx.y;
  const int rowTile = blockIdx.x;
  const int tid = threadIdx.x;
  const int lane = tid & 63;
  const int wave = tid >> 6;          // 0..7
  const int m16 = lane & 15;
  const int g = lane >> 4;            // k-group 0..3

  __shared__ unsigned short Bs[256 * 256];   // 128 KiB, swizzled rows of 512B

  const unsigned short* Bd = BcatT + d * 65536;

  // ---- stage B: 512 threads x 16 x 16B = 128KB, swizzled dest ----
#pragma unroll
  for (int it = 0; it < 16; ++it) {
    int flat = it * 512 + tid;        // chunk of 16B; 32 chunks per row
    int row = flat >> 5;
    int c = flat & 31;
    uint4 v = *(const uint4*)(Bd + row * 256 + c * 8);
    int kb = (c * 16) ^ ((row & 7) << 4);
    *(uint4*)((char*)Bs + row * 512 + kb) = v;
  }

  // ---- hoist A-frag loads for both 16-row chunks (hide under barrier) ----
  const int rowBase0 = rowTile * 256 + wave * 32;
  bf16x8 af0[8], af1[8];
  {
    int rbL = rowBase0 + m16; if (rbL > DEG_COUNT - 1) rbL = DEG_COUNT - 1;
    size_t gr = (size_t)d * DEG_COUNT + rbL;
#pragma unroll
    for (int ks = 0; ks < 4; ++ks)
      af0[ks] = *(const bf16x8*)(nsum + gr * 128 + ks * 32 + g * 8);
#pragma unroll
    for (int ks = 4; ks < 8; ++ks)
      af0[ks] = *(const bf16x8*)(atomsBf + gr * 128 + (ks - 4) * 32 + g * 8);
  }
  {
    int rbL = rowBase0 + 16 + m16; if (rbL > DEG_COUNT - 1) rbL = DEG_COUNT - 1;
    size_t gr = (size_t)d * DEG_COUNT + rbL;
#pragma unroll
    for (int ks = 0; ks < 4; ++ks)
      af1[ks] = *(const bf16x8*)(nsum + gr * 128 + ks * 32 + g * 8);
#pragma unroll
    for (int ks = 4; ks < 8; ++ks)
      af1[ks] = *(const bf16x8*)(atomsBf + gr * 128 + (ks - 4) * 32 + g * 8);
  }

  // ---- per-lane column constants ----
  float bias_[16], gam[8], bet[8];
#pragma unroll
  for (int ct = 0; ct < 16; ++ct) bias_[ct] = biascat[d * 256 + ct * 16 + m16];
#pragma unroll
  for (int ct = 0; ct < 8; ++ct) {
    gam[ct] = gamma[ct * 16 + m16];
    bet[ct] = beta[ct * 16 + m16];
  }

  __syncthreads();   // the only block-wide barrier

  const int ldsMask = (m16 & 7) << 4;

#pragma unroll
  for (int sub = 0; sub < 2; ++sub) {
    const int rowBase = rowBase0 + sub * 16;
    f32x4 acc[16];
#pragma unroll
    for (int ct = 0; ct < 16; ++ct) acc[ct] = (f32x4){0.f, 0.f, 0.f, 0.f};

#pragma unroll
    for (int ct = 0; ct < 16; ++ct) {
      const char* bbase = (const char*)Bs + (ct * 16 + m16) * 512;
      bf16x8 bf[8];
#pragma unroll
      for (int ks = 0; ks < 8; ++ks)
        bf[ks] = *(const bf16x8*)(bbase + ((ks * 64 + g * 16) ^ ldsMask));
#pragma unroll
      for (int ks = 0; ks < 8; ++ks) {
        bf16x8 a = (sub == 0) ? af0[ks] : af1[ks];
        acc[ct] = __builtin_amdgcn_mfma_f32_16x16x32_bf16(a, bf[ks], acc[ct], 0, 0, 0);
      }
    }

    // ---- epilogue: bias, LN over cols 0..127, stores (no barriers) ----
#pragma unroll
    for (int ct = 0; ct < 16; ++ct)
#pragma unroll
      for (int r = 0; r < 4; ++r) acc[ct][r] += bias_[ct];

    float s[4], qq[4];
#pragma unroll
    for (int r = 0; r < 4; ++r) {
      s[r] = 0.f; qq[r] = 0.f;
#pragma unroll
      for (int ct = 0; ct < 8; ++ct) {
        float v = acc[ct][r];
        s[r] += v; qq[r] += v * v;
      }
    }
#pragma unroll
    for (int off = 8; off >= 1; off >>= 1) {
#pragma unroll
      for (int r = 0; r < 4; ++r) {
        s[r]  += __shfl_xor(s[r],  off, 64);
        qq[r] += __shfl_xor(qq[r], off, 64);
      }
    }

#pragma unroll
    for (int r = 0; r < 4; ++r) {
      int rb = rowBase + g * 4 + r;
      float mean = s[r] * (1.0f / 128.0f);
      float var  = qq[r] * (1.0f / 128.0f) - mean * mean;
      float inv  = 1.0f / (sqrtf(var + 1e-5f) + 1e-5f);   // ref: sqrt(var+eps)+eps
      if (rb < DEG_COUNT) {
        size_t grow = (size_t)d * DEG_COUNT + rb;
#pragma unroll
        for (int ct = 0; ct < 8; ++ct)
          out0[grow * 128 + ct * 16 + m16] = gam[ct] * ((acc[ct][r] - mean) * inv) + bet[ct];
#pragma unroll
        for (int ct = 8; ct < 16; ++ct)
          gath[grow * 128 + (ct - 8) * 16 + m16] = f2bf(acc[ct][r]);
      }
    }
  }
}

// ---------------------------------------------------------------------------
// K4: read-only segment-max of final xn via per-block LDS table + monotonic
// int atomics (LN already applied inside k_gemm).
// ---------------------------------------------------------------------------
__global__ __launch_bounds__(512) void k_max(
    const float2* __restrict__ xnV,
    const int* __restrict__ membership,
    int* __restrict__ gmax)
{
  __shared__ int pmax[BATCH * 128];
  int tid = threadIdx.x;
  for (int i = tid; i < BATCH * 128; i += 512) pmax[i] = (int)NEG_INF_BITS;
  __syncthreads();
  int wave = tid >> 6, lane = tid & 63;
  const int rowsPerBlock = (N_ATOMS + gridDim.x - 1) / gridDim.x;
  int r0 = blockIdx.x * rowsPerBlock;
  int r1 = min(r0 + rowsPerBlock, N_ATOMS);
  for (int r = r0 + wave; r < r1; r += 8) {
    float2 x = xnV[(size_t)r * 64 + lane];
    int m = membership[r];
    int idx = m * 128 + lane * 2;
    if (x.x >= 0.f) atomicMax(&pmax[idx], __float_as_int(x.x));
    else            atomicMin((unsigned*)&pmax[idx], __float_as_uint(x.x));
    if (x.y >= 0.f) atomicMax(&pmax[idx + 1], __float_as_int(x.y));
    else            atomicMin((unsigned*)&pmax[idx + 1], __float_as_uint(x.y));
  }
  __syncthreads();
  for (int i = tid; i < BATCH * 128; i += 512) {
    int v = pmax[i];
    if (v != (int)NEG_INF_BITS) {
      if (v >= 0) atomicMax(&gmax[i], v);
      else        atomicMin((unsigned*)&gmax[i], (unsigned)v);
    }
  }
}

// K5: per-block LDS segment-sum of gathered (bf16 ws), merged via atomicAdd.
__global__ __launch_bounds__(512) void k_segsum(
    const unsigned* __restrict__ gathU,
    const int* __restrict__ membership,
    float* __restrict__ gsum)
{
  __shared__ float psum[BATCH * 128];
  int tid = threadIdx.x;
  for (int i = tid; i < BATCH * 128; i += 512) psum[i] = 0.f;
  __syncthreads();
  int wave = tid >> 6, lane = tid & 63;
  const int rowsPerBlock = (N_ATOMS + gridDim.x - 1) / gridDim.x;
  int r0 = blockIdx.x * rowsPerBlock;
  int r1 = min(r0 + rowsPerBlock, N_ATOMS);
  for (int r = r0 + wave; r < r1; r += 8) {
    unsigned x = gathU[(size_t)r * 64 + lane];
    int m = membership[r];
    atomicAdd(&psum[m * 128 + lane * 2],     bf2f((unsigned short)(x & 0xffff)));
    atomicAdd(&psum[m * 128 + lane * 2 + 1], bf2f((unsigned short)(x >> 16)));
  }
  __syncthreads();
  for (int i = tid; i < BATCH * 128; i += 512) {
    float v = psum[i];
    if (v != 0.f) atomicAdd(&gsum[i], v);
  }
}

// K6: norm gsum -> yn (out1); gmax -> g (out2). fp32.
__global__ __launch_bounds__(128) void k_final(
    const float* __restrict__ gsum,
    const int* __restrict__ gmax,
    const float* __restrict__ gamma,
    const float* __restrict__ beta,
    float* __restrict__ out1,
    float* __restrict__ out2)
{
  int m = blockIdx.x;
  int j = threadIdx.x;
  float s = gsum[m * 128 + j];
  out2[m * 128 + j] = __int_as_float(gmax[m * 128 + j]);

  float ws_ = s, wq = s * s;
#pragma unroll
  for (int off = 32; off >= 1; off >>= 1) {
    ws_ += __shfl_xor(ws_, off, 64);
    wq  += __shfl_xor(wq, off, 64);
  }
  __shared__ float red[4];
  int wave = j >> 6, lane = j & 63;
  if (lane == 0) { red[wave * 2] = ws_; red[wave * 2 + 1] = wq; }
  __syncthreads();
  float S = red[0] + red[2], Q = red[1] + red[3];
  float mean = S * (1.f / 128.f);
  float var = Q * (1.f / 128.f) - mean * mean;
  float inv = 1.f / (sqrtf(var + 1e-5f) + 1e-5f);
  float yn = gamma[j] * ((s - mean) * inv) + beta[j];
  out1[m * 128 + j] = yn;
}

// ---------------------------------------------------------------------------
extern "C" void kernel_launch(void* const* d_in, const int* in_sizes, int n_in,
                              void* d_out, int out_size, void* d_ws, size_t ws_size,
                              hipStream_t stream) {
  const float* atoms = (const float*)d_in[0];
  // d_in[1] = deg_slice (unused; buckets are static)
  const int* membership = (const int*)d_in[2];
  AdjPtrs adj;
  for (int i = 0; i < 10; ++i) adj.p[i] = (const int*)d_in[3 + i];
  const float* W     = (const float*)d_in[13];
  const float* b     = (const float*)d_in[14];
  const float* gamma = (const float*)d_in[15];
  const float* beta  = (const float*)d_in[16];

  char* ws = (char*)d_ws;
  size_t off = 0;
  unsigned short* atomsBf = (unsigned short*)(ws + off); off += (size_t)N_ATOMS * 128 * 2;
  unsigned short* nsum    = (unsigned short*)(ws + off); off += (size_t)N_ATOMS * 128 * 2;
  unsigned short* gath    = (unsigned short*)(ws + off); off += (size_t)N_ATOMS * 128 * 2;
  unsigned short* BcatT   = (unsigned short*)(ws + off); off += (size_t)11 * 256 * 256 * 2;
  float* biascat          = (float*)(ws + off);          off += (size_t)11 * 256 * 4;
  float* gsum             = (float*)(ws + off);          off += (size_t)BATCH * 128 * 4;
  int*   gmax             = (int*)(ws + off);            off += (size_t)BATCH * 128 * 4;

  float* out0 = (float*)d_out;
  float* out1 = out0 + (size_t)N_ATOMS * 128;
  float* out2 = out1 + 16384;

  hipLaunchKernelGGL(k_init, dim3((BATCH * 128 + 255) / 256), dim3(256), 0, stream, gsum, gmax);
  hipLaunchKernelGGL(k_cast, dim3(N_ATOMS * 128 / 4 / 256), dim3(256), 0, stream,
                     (const float4*)atoms, (ushort4*)atomsBf);
  hipLaunchKernelGGL(k_build_b, dim3((11 * 256 * 256 + 255) / 256), dim3(256), 0, stream, W, BcatT);
  hipLaunchKernelGGL(k_build_bias, dim3((11 * 256 + 255) / 256), dim3(256), 0, stream, b, biascat);
  hipLaunchKernelGGL(k_nsum, dim3(N_ATOMS / 4), dim3(256), 0, stream,
                     (const unsigned*)atomsBf, adj, (unsigned*)nsum);
  hipLaunchKernelGGL(k_gemm, dim3(118, 11), dim3(512), 0, stream,
                     atomsBf, nsum, BcatT, biascat, gamma, beta, out0, gath);
  hipLaunchKernelGGL(k_max, dim3(512), dim3(512), 0, stream,
                     (const float2*)out0, membership, gmax);
  hipLaunchKernelGGL(k_segsum, dim3(512), dim3(512), 0, stream,
                     (const unsigned*)gath, membership, gsum);
  hipLaunchKernelGGL(k_final, dim3(128), dim3(128), 0, stream,
                     gsum, gmax, gamma, beta, out1, out2);
}